// Round 8
// baseline (127.368 us; speedup 1.0000x reference)
//
#include <hip/hip_runtime.h>
#include <math.h>

#define WAVES_PER_BLOCK 4

typedef float v2f __attribute__((ext_vector_type(2)));
typedef float v4f __attribute__((ext_vector_type(4)));

__device__ __forceinline__ float fast_rcp(float x) { return __builtin_amdgcn_rcpf(x); }

// ---------------- DPP cross-lane primitives (no LDS, ~2cyc) ----------------
#define DPP_ROW_SHR(n)  (0x110 | (n))
#define DPP_WF_SL1      0x130   /* lane i <- lane i+1 (shfl_down 1) */
#define DPP_WF_SR1      0x138   /* lane i <- lane i-1 (shfl_up 1)   */
#define DPP_ROW_BCAST15 0x142
#define DPP_ROW_BCAST31 0x143

template <int CTRL, int RM = 0xf, int BM = 0xf, bool BC = false>
__device__ __forceinline__ float fdpp(float old_, float src) {
    return __int_as_float(__builtin_amdgcn_update_dpp(
        __float_as_int(old_), __float_as_int(src), CTRL, RM, BM, BC));
}

__device__ __forceinline__ float lane63_bcast(float x) {
    return __int_as_float(__builtin_amdgcn_readlane(__float_as_int(x), 63));
}
// uniform broadcast of lane `l` (compile-time) through an SGPR — VALU only
__device__ __forceinline__ float rdlane(float x, int l) {
    return __int_as_float(__builtin_amdgcn_readlane(__float_as_int(x), l));
}

// inclusive scan-add across 64 lanes (each step = ONE v_add_f32_dpp)
__device__ __forceinline__ float scan_add_dpp(float x) {
    x += fdpp<DPP_ROW_SHR(1)>(0.0f, x);
    x += fdpp<DPP_ROW_SHR(2)>(0.0f, x);
    x += fdpp<DPP_ROW_SHR(4)>(0.0f, x);
    x += fdpp<DPP_ROW_SHR(8)>(0.0f, x);
    x += fdpp<DPP_ROW_BCAST15, 0xa>(0.0f, x);
    x += fdpp<DPP_ROW_BCAST31, 0xc>(0.0f, x);
    return x;
}
// inclusive scan-mul across 64 lanes (identity = 1.0)
__device__ __forceinline__ float scan_mul_dpp(float x) {
    x *= fdpp<DPP_ROW_SHR(1)>(1.0f, x);
    x *= fdpp<DPP_ROW_SHR(2)>(1.0f, x);
    x *= fdpp<DPP_ROW_SHR(4)>(1.0f, x);
    x *= fdpp<DPP_ROW_SHR(8)>(1.0f, x);
    x *= fdpp<DPP_ROW_BCAST15, 0xa>(1.0f, x);
    x *= fdpp<DPP_ROW_BCAST31, 0xc>(1.0f, x);
    return x;
}
__device__ __forceinline__ float wave_sum_dpp(float x) {
    return lane63_bcast(scan_add_dpp(x));
}

__device__ __forceinline__ float softplus_f(float x) {
    return fmaxf(x, 0.0f) + __logf(1.0f + __expf(-fabsf(x)));
}
__device__ __forceinline__ float sigmoid_f(float x) {
    return fast_rcp(1.0f + __expf(-x));
}
__device__ __forceinline__ float clamp1(float x) {
    return fminf(fmaxf(x, -1.0f), 1.0f);
}

// ---- 2-level rank over a SORTED 64-entry wave-private LDS array ----------
// `own` = this lane's element (array[lane] == own): pivots a[8t+7] come from
// v_readlane; level 2 fetches the selected octant with two independent
// ds_read_b128.  Same count semantics as a binary search.  SORTED input only!
template <bool LE>
__device__ __forceinline__ int rank2(const float* a, float own, float x) {
    int o = 0;
#pragma unroll
    for (int t = 0; t < 8; ++t) {
        float p = rdlane(own, 8 * t + 7);
        o += (int)(LE ? (p <= x) : (p < x));
    }
    o = (o < 7) ? o : 7;            // x beyond a[63]: count within last octant
    const v4f q0 = *(const v4f*)&a[8 * o];
    const v4f q1 = *(const v4f*)&a[8 * o + 4];
    int cnt = 0;
    cnt += (int)(LE ? (q0.x <= x) : (q0.x < x));
    cnt += (int)(LE ? (q0.y <= x) : (q0.y < x));
    cnt += (int)(LE ? (q0.z <= x) : (q0.z < x));
    cnt += (int)(LE ? (q0.w <= x) : (q0.w < x));
    cnt += (int)(LE ? (q1.x <= x) : (q1.x < x));
    cnt += (int)(LE ? (q1.y <= x) : (q1.y < x));
    cnt += (int)(LE ? (q1.z <= x) : (q1.z < x));
    cnt += (int)(LE ? (q1.w <= x) : (q1.w < x));
    return 8 * o + cnt;
}

// Arena offsets (floats).  FT (phase-2) overlays CT/zarr/zmid (phase-1 only).
#define FT_OFF   0      /* [8 ch][132 rows], rows 0..128 used       (0..1055) */
#define CT_OFF   0      /* [65 rows][2]  coarse sigma buckets       (0..129)  */
#define ZARR_OFF 132    /* 64 sorted coarse z                       (528B %16=0) */
#define ZMID_OFF 196    /* 64 zmid (b32 gathers only)                         */
#define NZ_OFF   1056   /* 64: cdf then nz                         (4224B %16=0) */
#define ZALL_OFF 1120   /* 128 merged sorted z                     (4480B %16=0) */
#define ARENA_F  1248

__global__ __launch_bounds__(WAVES_PER_BLOCK * 64)
void nerf_render_kernel(const float* __restrict__ rays_o,
                        const float* __restrict__ rays_d,
                        const float* __restrict__ W1,      // [3,64]
                        const float* __restrict__ b1,      // [64]
                        const float* __restrict__ w_sigma, // [64,1]
                        const float* __restrict__ b_sigma, // [1]
                        const float* __restrict__ W_rgb,   // [64,3]
                        const float* __restrict__ b_rgb,   // [3]
                        float* __restrict__ out)           // [N,3]
{
    const int tid  = threadIdx.x;
    const int lane = tid & 63;
    const int wv   = tid >> 6;
    const int ray  = __builtin_amdgcn_readfirstlane(blockIdx.x * WAVES_PER_BLOCK + wv);

    // Wave-private LDS arena; intra-wave DS ops are program-ordered -> no
    // barriers anywhere (validated rounds 3-7).
    __shared__ __align__(16) float s_arena[WAVES_PER_BLOCK][ARENA_F];
    float* const AR    = s_arena[wv];
    float* const CT    = AR + CT_OFF;
    float* const zarr  = AR + ZARR_OFF;
    float* const zmid  = AR + ZMID_OFF;
    float* const FT    = AR + FT_OFF;
    float* const nzarr = AR + NZ_OFF;
    float* const zall  = AR + ZALL_OFF;

    // ---- ray load + normalize ----
    float ox = rays_o[ray * 3 + 0], oy = rays_o[ray * 3 + 1], oz = rays_o[ray * 3 + 2];
    float dx = rays_d[ray * 3 + 0], dy = rays_d[ray * 3 + 1], dz = rays_d[ray * 3 + 2];
    {
        float inv = __builtin_amdgcn_rsqf(dx * dx + dy * dy + dz * dz);
        dx *= inv; dy *= inv; dz *= inv;
    }

    // ---- near/far vs [-1,1]^3 ----
    float rx = fast_rcp(dx + 1e-15f);
    float ry = fast_rcp(dy + 1e-15f);
    float rz = fast_rcp(dz + 1e-15f);
    float t0x = (-1.0f - ox) * rx, t1x = (1.0f - ox) * rx;
    float t0y = (-1.0f - oy) * ry, t1y = (1.0f - oy) * ry;
    float t0z = (-1.0f - oz) * rz, t1z = (1.0f - oz) * rz;
    float nearv = fmaxf(fmaxf(fminf(t0x, t1x), fminf(t0y, t1y)), fminf(t0z, t1z));
    float farv  = fminf(fminf(fmaxf(t0x, t1x), fmaxf(t0y, t1y)), fmaxf(t0z, t1z));
    const bool miss = (farv < nearv);
    if (miss) { nearv = 1e9f; farv = 1e9f; }
    nearv = fmaxf(nearv, 0.05f);
    const float sample_dist = (farv - nearv) * (1.0f / 64.0f);

    // ---- per-lane unit weights (lane j owns hidden unit j) ----
    const float wS = w_sigma[lane];
    const float wR = W_rgb[3 * lane + 0];
    const float wG = W_rgb[3 * lane + 1];
    const float wB = W_rgb[3 * lane + 2];

    // ---- per-ray affine layer-1: a_j(z) = c_j + m_j*z ----
    float cj, mj;
    {
        float w1x = W1[lane], w1y = W1[64 + lane], w1z = W1[128 + lane];
        float eox = ox, eoy = oy, eoz = oz, msc = 1.0f;
        if (miss) {
            eox = clamp1(fmaf(dx, 1e9f, ox));
            eoy = clamp1(fmaf(dy, 1e9f, oy));
            eoz = clamp1(fmaf(dz, 1e9f, oz));
            msc = 0.0f;
        }
        cj = fmaf(eox, w1x, fmaf(eoy, w1y, fmaf(eoz, w1z, b1[lane])));
        mj = msc * fmaf(dx, w1x, fmaf(dy, w1y, dz * w1z));
    }

    // ---- piecewise-linear MLP, bucket-prefix form ------------------------
    // relu(c+mz): m>0 unit turns ON where z > knee (payload +w(m,c)); m<0
    // unit is always-on base w(c+mz) with turn-OFF payload -w(m,c); m==0
    // contributes w*relu(c).  A_X(z) = Qp_X + sum_j am_Xj [knee_j < z], and
    // [knee_j < z_e] <=> e_j <= e where e_j = #{eval pts <= knee_j} (exact,
    // tie-safe) -> scatter payloads into eval-indexed buckets, prefix-scan.
    const bool m0 = (mj == 0.0f);           // includes all lanes of miss rays
    const bool mneg = (mj < 0.0f);
    float knee = m0 ? 3e38f : (-cj * fast_rcp(mj));
    float t  = m0 ? 0.0f : (mneg ? -1.0f : 1.0f);
    float tm = t * mj, tc = t * cj;
    float qc = mneg ? mj : 0.0f;
    float pc = mneg ? cj : (m0 ? fmaxf(cj, 0.0f) : 0.0f);

    // base sums (order-independent) + biases
    const float bs0 = b_sigma[0];
    float QpS = wave_sum_dpp(wS * qc), PpS = wave_sum_dpp(wS * pc) + bs0;
    float QpR = wave_sum_dpp(wR * qc), PpR = wave_sum_dpp(wR * pc) + b_rgb[0];
    float QpG = wave_sum_dpp(wG * qc), PpG = wave_sum_dpp(wG * pc) + b_rgb[1];
    float QpB = wave_sum_dpp(wB * qc), PpB = wave_sum_dpp(wB * pc) + b_rgb[2];

    // ---- coarse grid + coarse sigma table (65 buckets x {am,ac}) ---------
    float z = nearv + (farv - nearv) * ((float)lane * (1.0f / 63.0f));
    zarr[lane] = z;                              // sorted (monotone in lane)
    *(v2f*)&CT[2 * lane] = (v2f){0.0f, 0.0f};    // zero rows 0..63
    if (lane == 0) *(v2f*)&CT[128] = (v2f){0.0f, 0.0f};  // row 64

    int ej = rank2<true>(zarr, z, knee);         // #{coarse z <= knee}, 0..64
    atomicAdd(&CT[2 * ej + 0], wS * tm);         // ds_add_f32, wave-private
    atomicAdd(&CT[2 * ej + 1], wS * tc);

    v2f ct = *(const v2f*)&CT[2 * lane];
    float SA = scan_add_dpp(ct.x);               // incl prefix through bucket=lane
    float SB = scan_add_dpp(ct.y);
    float sigma = softplus_f(fmaf(QpS + SA, z, PpS + SB));

    // ---- coarse alpha compositing -> weights ----
    float z_next = fdpp<DPP_WF_SL1>(0.0f, z);
    float delta  = (lane < 63) ? (z_next - z) : sample_dist;
    float alpha  = 1.0f - __expf(-delta * sigma);
    float v      = 1.0f - alpha + 1e-15f;
    float incl   = scan_mul_dpp(v);
    float trans  = fdpp<DPP_WF_SR1>(1.0f, incl);   // lane0 -> 1.0
    float w = alpha * trans;

    // ---- sample_pdf: unnormalized scan, total from lane63 of same scan ----
    float wgt = (lane >= 1 && lane <= 62) ? (w + 1e-5f) : 0.0f;
    float cumw = scan_add_dpp(wgt);
    float total = lane63_bcast(cumw);
    float cdf_incl = cumw * fast_rcp(total);

    float cdfv = (lane < 63) ? cdf_incl : 2.0f;    // sentinel for the search
    zmid [lane] = 0.5f * (z + z_next);             // lane63 slot never read
    nzarr[lane] = cdfv;                            // cdf array (reused for nz)

    float u = 0.0078125f + (float)lane * 0.015625f;
    int ind = rank2<true>(nzarr, cdfv, u);
    int below = ind - 1;
    int above = (ind < 62) ? ind : 62;
    float cb = nzarr[below], ca = nzarr[above];
    float bb = zmid [below], ba = zmid [above];
    float denom = ca - cb;
    if (denom < 1e-5f) denom = 1.0f;
    float tt = (u - cb) * fast_rcp(denom);
    float nz = fmaf(tt, ba - bb, bb);

    // ---- rank-merge concat(z, new_z) -> 128 sorted ----
    nzarr[lane] = nz;                              // overwrite cdf (done with it)
    int pa  = lane + rank2<false>(nzarr, nz, z);
    int pb2 = lane + rank2<true >(zarr,  z,  nz);
    zall[pa]  = z;
    zall[pb2] = nz;

    v2f za = *(const v2f*)&zall[2 * lane];
    float za0 = za.x;
    float za1 = za.y;

    // ---- fine table: 129 buckets x 8 ch (channel-major, 2-way-conflict) --
    int fj = rank2<true>(nzarr, nz, knee);         // #{nz <= knee}
    int ep = ej + fj;                              // #{zall <= knee}, 0..128

    // zero own rows (2l, 2l+1) of each channel + row 128 (lane0); overlays
    // CT/zarr/zmid which are all dead by here.
#pragma unroll
    for (int ch = 0; ch < 8; ++ch) {
        *(v2f*)&FT[132 * ch + 2 * lane] = (v2f){0.0f, 0.0f};
    }
    if (lane == 0) {
#pragma unroll
        for (int ch = 0; ch < 8; ++ch) FT[132 * ch + 128] = 0.0f;
    }
    atomicAdd(&FT[132 * 0 + ep], wS * tm);
    atomicAdd(&FT[132 * 1 + ep], wS * tc);
    atomicAdd(&FT[132 * 2 + ep], wR * tm);
    atomicAdd(&FT[132 * 3 + ep], wR * tc);
    atomicAdd(&FT[132 * 4 + ep], wG * tm);
    atomicAdd(&FT[132 * 5 + ep], wG * tc);
    atomicAdd(&FT[132 * 6 + ep], wB * tm);
    atomicAdd(&FT[132 * 7 + ep], wB * tc);

    // lane owns bucket rows 2l (za0) and 2l+1 (za1): scan pair-sums ->
    // S1 = incl prefix through 2l+1; S0 = S1 - bucket(2l+1).
    v2f bS = *(const v2f*)&FT[132 * 0 + 2 * lane];
    v2f cS = *(const v2f*)&FT[132 * 1 + 2 * lane];
    v2f bR = *(const v2f*)&FT[132 * 2 + 2 * lane];
    v2f cR = *(const v2f*)&FT[132 * 3 + 2 * lane];
    v2f bG = *(const v2f*)&FT[132 * 4 + 2 * lane];
    v2f cG = *(const v2f*)&FT[132 * 5 + 2 * lane];
    v2f bb2 = *(const v2f*)&FT[132 * 6 + 2 * lane];
    v2f cB = *(const v2f*)&FT[132 * 7 + 2 * lane];

    float s1S = scan_add_dpp(bS.x + bS.y), s1Sc = scan_add_dpp(cS.x + cS.y);
    float s1R = scan_add_dpp(bR.x + bR.y), s1Rc = scan_add_dpp(cR.x + cR.y);
    float s1G = scan_add_dpp(bG.x + bG.y), s1Gc = scan_add_dpp(cG.x + cG.y);
    float s1B = scan_add_dpp(bb2.x + bb2.y), s1Bc = scan_add_dpp(cB.x + cB.y);

    float preS1 = fmaf(QpS + s1S, za1, PpS + s1Sc);
    float preR1 = fmaf(QpR + s1R, za1, PpR + s1Rc);
    float preG1 = fmaf(QpG + s1G, za1, PpG + s1Gc);
    float preB1 = fmaf(QpB + s1B, za1, PpB + s1Bc);
    float preS0 = fmaf(QpS + (s1S - bS.y), za0, PpS + (s1Sc - cS.y));
    float preR0 = fmaf(QpR + (s1R - bR.y), za0, PpR + (s1Rc - cR.y));
    float preG0 = fmaf(QpG + (s1G - bG.y), za0, PpG + (s1Gc - cG.y));
    float preB0 = fmaf(QpB + (s1B - bb2.y), za0, PpB + (s1Bc - cB.y));

    float sg0 = softplus_f(preS0), sg1 = softplus_f(preS1);
    float r0  = sigmoid_f (preR0), r1  = sigmoid_f (preR1);
    float g0  = sigmoid_f (preG0), g1  = sigmoid_f (preG1);
    float bl0 = sigmoid_f (preB0), bl1 = sigmoid_f (preB1);

    // ---- fine compositing over 128 samples (2/lane) ----
    float zn0 = fdpp<DPP_WF_SL1>(0.0f, za0);
    float d0f = za1 - za0;
    float d1f = (lane < 63) ? (zn0 - za1) : sample_dist;
    float a0 = 1.0f - __expf(-d0f * sg0);
    float a1 = 1.0f - __expf(-d1f * sg1);
    float v0 = 1.0f - a0 + 1e-15f;
    float v1 = 1.0f - a1 + 1e-15f;
    float local = v0 * v1;
    float incl2 = scan_mul_dpp(local);
    float eprod = fdpp<DPP_WF_SR1>(1.0f, incl2);   // lane0 -> 1.0
    float w0 = a0 * eprod;
    float w1 = a1 * (eprod * v0);

    float wsum = wave_sum_dpp(w0 + w1);
    float rs   = wave_sum_dpp(fmaf(w0, r0,  w1 * r1));
    float gs   = wave_sum_dpp(fmaf(w0, g0,  w1 * g1));
    float bs   = wave_sum_dpp(fmaf(w0, bl0, w1 * bl1));

    if (lane == 0) {
        float bg = 1.0f - wsum;
        out[ray * 3 + 0] = rs + bg;
        out[ray * 3 + 1] = gs + bg;
        out[ray * 3 + 2] = bs + bg;
    }
}

extern "C" void kernel_launch(void* const* d_in, const int* in_sizes, int n_in,
                              void* d_out, int out_size, void* d_ws, size_t ws_size,
                              hipStream_t stream) {
    const float* rays_o  = (const float*)d_in[0];
    const float* rays_d  = (const float*)d_in[1];
    const float* W1      = (const float*)d_in[2];
    const float* b1      = (const float*)d_in[3];
    const float* w_sigma = (const float*)d_in[4];
    const float* b_sigma = (const float*)d_in[5];
    const float* W_rgb   = (const float*)d_in[6];
    const float* b_rgb   = (const float*)d_in[7];
    float* out = (float*)d_out;

    const int n_rays = in_sizes[0] / 3;
    dim3 grid((n_rays + WAVES_PER_BLOCK - 1) / WAVES_PER_BLOCK);
    dim3 block(WAVES_PER_BLOCK * 64);
    hipLaunchKernelGGL(nerf_render_kernel, grid, block, 0, stream,
                       rays_o, rays_d, W1, b1, w_sigma, b_sigma, W_rgb, b_rgb, out);
}

// Round 9
// 91.663 us; speedup vs baseline: 1.3895x; 1.3895x over previous
//
#include <hip/hip_runtime.h>
#include <math.h>

#define WAVES_PER_BLOCK 4

typedef float v2f __attribute__((ext_vector_type(2)));
typedef float v4f __attribute__((ext_vector_type(4)));

__device__ __forceinline__ float fast_rcp(float x) { return __builtin_amdgcn_rcpf(x); }

// ---------------- DPP cross-lane primitives (no LDS, ~2cyc) ----------------
#define DPP_ROW_SHR(n)  (0x110 | (n))
#define DPP_WF_SL1      0x130   /* lane i <- lane i+1 (shfl_down 1) */
#define DPP_WF_SR1      0x138   /* lane i <- lane i-1 (shfl_up 1)   */
#define DPP_ROW_BCAST15 0x142
#define DPP_ROW_BCAST31 0x143

template <int CTRL, int RM = 0xf, int BM = 0xf, bool BC = false>
__device__ __forceinline__ float fdpp(float old_, float src) {
    return __int_as_float(__builtin_amdgcn_update_dpp(
        __float_as_int(old_), __float_as_int(src), CTRL, RM, BM, BC));
}

__device__ __forceinline__ float lane63_bcast(float x) {
    return __int_as_float(__builtin_amdgcn_readlane(__float_as_int(x), 63));
}
// uniform broadcast of lane `l` (compile-time) through an SGPR — VALU only
__device__ __forceinline__ float rdlane(float x, int l) {
    return __int_as_float(__builtin_amdgcn_readlane(__float_as_int(x), l));
}

// inclusive scan-add across 64 lanes (each step = ONE v_add_f32_dpp)
__device__ __forceinline__ float scan_add_dpp(float x) {
    x += fdpp<DPP_ROW_SHR(1)>(0.0f, x);
    x += fdpp<DPP_ROW_SHR(2)>(0.0f, x);
    x += fdpp<DPP_ROW_SHR(4)>(0.0f, x);
    x += fdpp<DPP_ROW_SHR(8)>(0.0f, x);
    x += fdpp<DPP_ROW_BCAST15, 0xa>(0.0f, x);
    x += fdpp<DPP_ROW_BCAST31, 0xc>(0.0f, x);
    return x;
}
// inclusive scan-mul across 64 lanes (identity = 1.0)
__device__ __forceinline__ float scan_mul_dpp(float x) {
    x *= fdpp<DPP_ROW_SHR(1)>(1.0f, x);
    x *= fdpp<DPP_ROW_SHR(2)>(1.0f, x);
    x *= fdpp<DPP_ROW_SHR(4)>(1.0f, x);
    x *= fdpp<DPP_ROW_SHR(8)>(1.0f, x);
    x *= fdpp<DPP_ROW_BCAST15, 0xa>(1.0f, x);
    x *= fdpp<DPP_ROW_BCAST31, 0xc>(1.0f, x);
    return x;
}
__device__ __forceinline__ float wave_sum_dpp(float x) {
    return lane63_bcast(scan_add_dpp(x));
}

__device__ __forceinline__ float softplus_f(float x) {
    return fmaxf(x, 0.0f) + __logf(1.0f + __expf(-fabsf(x)));
}
__device__ __forceinline__ float sigmoid_f(float x) {
    return fast_rcp(1.0f + __expf(-x));
}
__device__ __forceinline__ float clamp1(float x) {
    return fminf(fmaxf(x, -1.0f), 1.0f);
}

// ---- 2-level rank over a SORTED 64-entry wave-private LDS array ----------
// `own` = this lane's element (array[lane] == own): pivots a[8t+7] come from
// v_readlane; level 2 fetches the selected octant with two independent
// ds_read_b128.  Same count semantics as a binary search.  SORTED input only!
template <bool LE>
__device__ __forceinline__ int rank2(const float* a, float own, float x) {
    int o = 0;
#pragma unroll
    for (int t = 0; t < 8; ++t) {
        float p = rdlane(own, 8 * t + 7);
        o += (int)(LE ? (p <= x) : (p < x));
    }
    o = (o < 7) ? o : 7;            // x beyond a[63]: count within last octant
    const v4f q0 = *(const v4f*)&a[8 * o];
    const v4f q1 = *(const v4f*)&a[8 * o + 4];
    int cnt = 0;
    cnt += (int)(LE ? (q0.x <= x) : (q0.x < x));
    cnt += (int)(LE ? (q0.y <= x) : (q0.y < x));
    cnt += (int)(LE ? (q0.z <= x) : (q0.z < x));
    cnt += (int)(LE ? (q0.w <= x) : (q0.w < x));
    cnt += (int)(LE ? (q1.x <= x) : (q1.x < x));
    cnt += (int)(LE ? (q1.y <= x) : (q1.y < x));
    cnt += (int)(LE ? (q1.z <= x) : (q1.z < x));
    cnt += (int)(LE ? (q1.w <= x) : (q1.w < x));
    return 8 * o + cnt;
}

__global__ __launch_bounds__(WAVES_PER_BLOCK * 64)
void nerf_render_kernel(const float* __restrict__ rays_o,
                        const float* __restrict__ rays_d,
                        const float* __restrict__ W1,      // [3,64]
                        const float* __restrict__ b1,      // [64]
                        const float* __restrict__ w_sigma, // [64,1]
                        const float* __restrict__ b_sigma, // [1]
                        const float* __restrict__ W_rgb,   // [64,3]
                        const float* __restrict__ b_rgb,   // [3]
                        float* __restrict__ out)           // [N,3]
{
    const int tid  = threadIdx.x;
    const int lane = tid & 63;
    const int wv   = tid >> 6;
    const int ray  = __builtin_amdgcn_readfirstlane(blockIdx.x * WAVES_PER_BLOCK + wv);

    // Wave-private LDS; intra-wave DS ops are program-ordered -> no barriers.
    // s_pref: table [65 slots][8: {A_s,B_s,A_r,B_r,A_g,B_g,A_b,B_b}] where
    // pre_X(z) = fma(A_k, z, B_k), k = #knees < z  (A=Qp+prefA, B=Pp+prefB).
    __shared__ __align__(16) float s_pref[WAVES_PER_BLOCK][65][8];
    __shared__ __align__(16) float s_kne [WAVES_PER_BLOCK][64];  // sorted knees
    __shared__ __align__(16) float s_zmid[WAVES_PER_BLOCK][64];  // keys, then zmid/z
    __shared__ __align__(16) float s_cdf [WAVES_PER_BLOCK][64];
    __shared__ __align__(16) float s_zall[WAVES_PER_BLOCK][128];

    // ---- ray load + normalize ----
    float ox = rays_o[ray * 3 + 0], oy = rays_o[ray * 3 + 1], oz = rays_o[ray * 3 + 2];
    float dx = rays_d[ray * 3 + 0], dy = rays_d[ray * 3 + 1], dz = rays_d[ray * 3 + 2];
    {
        float inv = __builtin_amdgcn_rsqf(dx * dx + dy * dy + dz * dz);
        dx *= inv; dy *= inv; dz *= inv;
    }

    // ---- near/far vs [-1,1]^3 ----
    float rx = fast_rcp(dx + 1e-15f);
    float ry = fast_rcp(dy + 1e-15f);
    float rz = fast_rcp(dz + 1e-15f);
    float t0x = (-1.0f - ox) * rx, t1x = (1.0f - ox) * rx;
    float t0y = (-1.0f - oy) * ry, t1y = (1.0f - oy) * ry;
    float t0z = (-1.0f - oz) * rz, t1z = (1.0f - oz) * rz;
    float nearv = fmaxf(fmaxf(fminf(t0x, t1x), fminf(t0y, t1y)), fminf(t0z, t1z));
    float farv  = fminf(fminf(fmaxf(t0x, t1x), fmaxf(t0y, t1y)), fmaxf(t0z, t1z));
    const bool miss = (farv < nearv);
    if (miss) { nearv = 1e9f; farv = 1e9f; }
    nearv = fmaxf(nearv, 0.05f);
    const float sample_dist = (farv - nearv) * (1.0f / 64.0f);

    // ---- per-lane unit weights (lane j owns hidden unit j) ----
    const float wS = w_sigma[lane];
    const float wR = W_rgb[3 * lane + 0];
    const float wG = W_rgb[3 * lane + 1];
    const float wB = W_rgb[3 * lane + 2];

    // ---- per-ray affine layer-1: a_j(z) = c_j + m_j*z ----
    float cj, mj;
    {
        float w1x = W1[lane], w1y = W1[64 + lane], w1z = W1[128 + lane];
        float eox = ox, eoy = oy, eoz = oz, msc = 1.0f;
        if (miss) {
            eox = clamp1(fmaf(dx, 1e9f, ox));
            eoy = clamp1(fmaf(dy, 1e9f, oy));
            eoz = clamp1(fmaf(dz, 1e9f, oz));
            msc = 0.0f;
        }
        cj = fmaf(eox, w1x, fmaf(eoy, w1y, fmaf(eoz, w1z, b1[lane])));
        mj = msc * fmaf(dx, w1x, fmaf(dy, w1y, dz * w1z));
    }

    // ---- piecewise-linear MLP setup (sign form) --------------------------
    // relu(c+mz): m>0 unit turns ON at knee (payload +w(m,c)); m<0 unit is ON
    // below its knee (base w(c+mz), payload -w(m,c) turns it off); m==0 unit
    // contributes w*relu(c) always.  pre_X(z) = (Pp+prefB_k) + (Qp+prefA_k)z.
    const bool m0 = (mj == 0.0f);           // includes all lanes of miss rays
    const bool mneg = (mj < 0.0f);
    float knee = m0 ? 3e38f : (-cj * fast_rcp(mj));
    float t  = m0 ? 0.0f : (mneg ? -1.0f : 1.0f);
    float tm = t * mj, tc = t * cj;
    float pc = mneg ? cj : (m0 ? fmaxf(cj, 0.0f) : 0.0f);  // always-on base /wX
    float qc = mneg ? mj : 0.0f;

    // ---- unique 32-bit sort key: ordered-uint(knee), low 6 bits = lane ---
    // Total order with stable tie-break -> scatter is a bijection (no
    // zero-init needed).  Truncating 6 mantissa LSBs only reorders knees
    // within 2^-17 relative of each other: misclassification window ~1e-5
    // wide where the unit's contribution is ~0 -> error negligible.
    unsigned kb  = __float_as_uint(knee);
    unsigned ord = kb ^ ((kb & 0x80000000u) ? 0xFFFFFFFFu : 0x80000000u);
    unsigned key = (ord & ~63u) | (unsigned)lane;

    float* keyU = s_zmid[wv];    // key array (dead after the rank below)
    float* kneeS = s_kne[wv];
    keyU[lane] = __uint_as_float(key);

    // brute-force rank over unique keys: 1 cmp + 1 add per element
    int p = 0;
#pragma unroll
    for (int g = 0; g < 16; ++g) {
        v4f q = *(const v4f*)&keyU[4 * g];
        p += (int)(__float_as_uint(q.x) < key);
        p += (int)(__float_as_uint(q.y) < key);
        p += (int)(__float_as_uint(q.z) < key);
        p += (int)(__float_as_uint(q.w) < key);
    }
    kneeS[p] = knee;
    *(v4f*)&s_pref[wv][p][0] = (v4f){wS * tm, wS * tc, wR * tm, wR * tc};
    *(v4f*)&s_pref[wv][p][4] = (v4f){wG * tm, wG * tc, wB * tm, wB * tc};

    // base sums (order-independent) — these are the table's k=0 values
    const float bs0 = b_sigma[0];
    float QpS = wave_sum_dpp(wS * qc), PpS = wave_sum_dpp(wS * pc) + bs0;
    float QpR = wave_sum_dpp(wR * qc), PpR = wave_sum_dpp(wR * pc) + b_rgb[0];
    float QpG = wave_sum_dpp(wG * qc), PpG = wave_sum_dpp(wG * pc) + b_rgb[1];
    float QpB = wave_sum_dpp(wB * qc), PpB = wave_sum_dpp(wB * pc) + b_rgb[2];

    // read payloads in sorted order, scan, write table slot lane+1 (= prefix
    // over first lane+1 sorted elements, plus the base) ; lane0 writes slot 0
    v4f d0 = *(const v4f*)&s_pref[wv][lane][0];
    v4f d1 = *(const v4f*)&s_pref[wv][lane][4];
    float own_knee = kneeS[lane];

    float iAs = scan_add_dpp(d0.x) + QpS, iBs = scan_add_dpp(d0.y) + PpS;
    float iAr = scan_add_dpp(d0.z) + QpR, iBr = scan_add_dpp(d0.w) + PpR;
    float iAg = scan_add_dpp(d1.x) + QpG, iBg = scan_add_dpp(d1.y) + PpG;
    float iAb = scan_add_dpp(d1.z) + QpB, iBb = scan_add_dpp(d1.w) + PpB;

    *(v4f*)&s_pref[wv][lane + 1][0] = (v4f){iAs, iBs, iAr, iBr};
    *(v4f*)&s_pref[wv][lane + 1][4] = (v4f){iAg, iBg, iAb, iBb};
    if (lane == 0) {
        *(v4f*)&s_pref[wv][0][0] = (v4f){QpS, PpS, QpR, PpR};
        *(v4f*)&s_pref[wv][0][4] = (v4f){QpG, PpG, QpB, PpB};
    }

    // ---- coarse samples + sigma via one-fma table eval ----
    float z = nearv + (farv - nearv) * ((float)lane * (1.0f / 63.0f));
    float sigma;
    {
        int k = rank2<false>(kneeS, own_knee, z);
        v2f ab = *(const v2f*)&s_pref[wv][k][0];   // {A_s, B_s}
        sigma = softplus_f(fmaf(ab.x, z, ab.y));
    }

    // ---- coarse alpha compositing -> weights ----
    float z_next = fdpp<DPP_WF_SL1>(0.0f, z);
    float delta  = (lane < 63) ? (z_next - z) : sample_dist;
    float alpha  = 1.0f - __expf(-delta * sigma);
    float v      = 1.0f - alpha + 1e-15f;
    float incl   = scan_mul_dpp(v);
    float trans  = fdpp<DPP_WF_SR1>(1.0f, incl);   // lane0 -> 1.0
    float w = alpha * trans;

    // ---- sample_pdf: unnormalized scan, total from lane63 of same scan ----
    float wgt = (lane >= 1 && lane <= 62) ? (w + 1e-5f) : 0.0f;
    float cumw = scan_add_dpp(wgt);
    float total = lane63_bcast(cumw);
    float cdf_incl = cumw * fast_rcp(total);

    float zmid = 0.5f * (z + z_next);
    float cdfv = (lane < 63) ? cdf_incl : 2.0f;    // sentinel
    s_zmid[wv][lane] = (lane < 63) ? zmid : 0.0f;  // keyU dead -> reuse
    s_cdf [wv][lane] = cdfv;

    float u = 0.0078125f + (float)lane * 0.015625f;
    int ind = rank2<true>(s_cdf[wv], cdfv, u);
    int below = ind - 1;
    int above = (ind < 62) ? ind : 62;
    float cb = s_cdf[wv][below], ca = s_cdf[wv][above];
    float bb = s_zmid[wv][below], ba = s_zmid[wv][above];
    float denom = ca - cb;
    if (denom < 1e-5f) denom = 1.0f;
    float tt = (u - cb) * fast_rcp(denom);
    float nz = fmaf(tt, ba - bb, bb);

    // ---- rank-merge concat(z, new_z) -> 128 sorted ----
    s_zmid[wv][lane] = z;      // array of z's   (z_lane == own)
    s_cdf [wv][lane] = nz;     // array of nz's  (nz     == own)
    int pa  = lane + rank2<false>(s_cdf [wv], nz, z);
    int pb2 = lane + rank2<true >(s_zmid[wv], z,  nz);
    s_zall[wv][pa]  = z;
    s_zall[wv][pb2] = nz;

    v2f za = *(const v2f*)&s_zall[wv][2 * lane];
    float za0 = za.x;
    float za1 = za.y;

    // ---- fine MLP via one-fma table eval (both samples, 4 channels) ----
    int k0 = rank2<false>(kneeS, own_knee, za0);
    int k1 = rank2<false>(kneeS, own_knee, za1);
    v4f A0 = *(const v4f*)&s_pref[wv][k0][0];
    v4f A1 = *(const v4f*)&s_pref[wv][k0][4];
    v4f B0 = *(const v4f*)&s_pref[wv][k1][0];
    v4f B1 = *(const v4f*)&s_pref[wv][k1][4];

    float sg0 = softplus_f(fmaf(A0.x, za0, A0.y));
    float r0  = sigmoid_f (fmaf(A0.z, za0, A0.w));
    float g0  = sigmoid_f (fmaf(A1.x, za0, A1.y));
    float bl0 = sigmoid_f (fmaf(A1.z, za0, A1.w));
    float sg1 = softplus_f(fmaf(B0.x, za1, B0.y));
    float r1  = sigmoid_f (fmaf(B0.z, za1, B0.w));
    float g1  = sigmoid_f (fmaf(B1.x, za1, B1.y));
    float bl1 = sigmoid_f (fmaf(B1.z, za1, B1.w));

    // ---- fine compositing over 128 samples (2/lane) ----
    float zn0 = fdpp<DPP_WF_SL1>(0.0f, za0);
    float d0f = za1 - za0;
    float d1f = (lane < 63) ? (zn0 - za1) : sample_dist;
    float a0 = 1.0f - __expf(-d0f * sg0);
    float a1 = 1.0f - __expf(-d1f * sg1);
    float v0 = 1.0f - a0 + 1e-15f;
    float v1 = 1.0f - a1 + 1e-15f;
    float local = v0 * v1;
    float incl2 = scan_mul_dpp(local);
    float eprod = fdpp<DPP_WF_SR1>(1.0f, incl2);   // lane0 -> 1.0
    float w0 = a0 * eprod;
    float w1 = a1 * (eprod * v0);

    float wsum = wave_sum_dpp(w0 + w1);
    float rs   = wave_sum_dpp(fmaf(w0, r0,  w1 * r1));
    float gs   = wave_sum_dpp(fmaf(w0, g0,  w1 * g1));
    float bs   = wave_sum_dpp(fmaf(w0, bl0, w1 * bl1));

    if (lane == 0) {
        float bg = 1.0f - wsum;
        out[ray * 3 + 0] = rs + bg;
        out[ray * 3 + 1] = gs + bg;
        out[ray * 3 + 2] = bs + bg;
    }
}

extern "C" void kernel_launch(void* const* d_in, const int* in_sizes, int n_in,
                              void* d_out, int out_size, void* d_ws, size_t ws_size,
                              hipStream_t stream) {
    const float* rays_o  = (const float*)d_in[0];
    const float* rays_d  = (const float*)d_in[1];
    const float* W1      = (const float*)d_in[2];
    const float* b1      = (const float*)d_in[3];
    const float* w_sigma = (const float*)d_in[4];
    const float* b_sigma = (const float*)d_in[5];
    const float* W_rgb   = (const float*)d_in[6];
    const float* b_rgb   = (const float*)d_in[7];
    float* out = (float*)d_out;

    const int n_rays = in_sizes[0] / 3;
    dim3 grid((n_rays + WAVES_PER_BLOCK - 1) / WAVES_PER_BLOCK);
    dim3 block(WAVES_PER_BLOCK * 64);
    hipLaunchKernelGGL(nerf_render_kernel, grid, block, 0, stream,
                       rays_o, rays_d, W1, b1, w_sigma, b_sigma, W_rgb, b_rgb, out);
}